// Round 10
// baseline (239.880 us; speedup 1.0000x reference)
//
#include <hip/hip_runtime.h>
#include <cstdint>
#include <cstddef>

#define NPTS 4096
#define KNN  16
#define INV_DEG (1.0f / 17.0f)
#define CAP  48   // knn per-point candidate buffer (entries [48..64) = slot staging)
#define TS   256  // candidate tile (float4 x/y/z/sq = 4 KB) — R10: 512->256 for 12KB blocks

typedef unsigned long long u64;
typedef unsigned int u32;
typedef float v2f __attribute__((ext_vector_type(2)));

// raw sentinel {d2=+inf, j=0xFFFFFFFF}: converts above any real candidate
#define RAWSENT 0x7F800000FFFFFFFFull

__device__ __forceinline__ float unmapmono(u32 m) {
  u32 u = (m & 0x80000000u) ? (m ^ 0x80000000u) : ~m;
  return __uint_as_float(u);
}

// ---------------------------------------------------------------------------
// K1: exact KNN (top-16 smallest d2, tie -> lower index) + fused enc1.
// Ledger: (R3) no min-waves hint -> 45MB scratch spill; (R4) flush = LDS
// rank-select, NOT shfl bitonic; (R5/R6) LDS-residency: 28KB->2 blk, 16KB->
// ~3 blk (72.5% occ); (R7/R8 FAIL) grid must cover all 32768 points.
// R10: TS=256 -> 12KB/block targeting 4 blocks/CU.
// ---------------------------------------------------------------------------
__global__ __launch_bounds__(512) void knn_kernel(const float* __restrict__ feats,
                                                  const float* __restrict__ W1,
                                                  const float* __restrict__ b1,
                                                  int* __restrict__ nbr,
                                                  float* __restrict__ x1) {
#pragma clang fp contract(off)
  __shared__ float4 sc[TS];       // 4 KB: {x, y, z, sq}
  __shared__ u64 sbuf[8][2][64];  // 8 KB

  const int b = blockIdx.x >> 8;
  const int pbase = (blockIdx.x & 255) * 16;
  const float* fb = feats + (size_t)b * NPTS * 6;
  const int wave = threadIdx.x >> 6;
  const int lane = threadIdx.x & 63;

  int ip[2];
  float xi[2], yi[2], zi[2], sqi[2], tau[2];
  u64 slot[2];
  int cnt[2];
#pragma unroll
  for (int p = 0; p < 2; ++p) {
    ip[p] = pbase + wave * 2 + p;
    const float* fr = fb + (size_t)ip[p] * 6;
    xi[p] = fr[0]; yi[p] = fr[1]; zi[p] = fr[2];
    sqi[p] = __fadd_rn(__fadd_rn(__fmul_rn(xi[p], xi[p]), __fmul_rn(yi[p], yi[p])),
                       __fmul_rn(zi[p], zi[p]));
    tau[p] = __uint_as_float(0x7f800000u);  // +inf: batch 0 all-pass bootstraps
    slot[p] = ~0ull;
    cnt[p] = 0;
  }

  // LDS rank-select merge of {<=48 raw buffered} U {16 mono slots}.
  auto flush = [&](int p) {
    u64* wb = &sbuf[wave][p][0];
    if (lane >= cnt[p] && lane < CAP) wb[lane] = RAWSENT;  // clear unused (raw)
    if (lane < KNN) wb[CAP + lane] = slot[p];              // stage slots (mono)
    u64 myk = wb[lane];
    if (lane < CAP) {  // raw -> mono; neutralize self
      u32 hi = (u32)(myk >> 32);
      hi ^= ((u32)((int)hi >> 31) | 0x80000000u);
      myk = ((u64)hi << 32) | (u32)myk;
      if ((u32)myk == (u32)ip[p]) myk = ~0ull;
      wb[lane] = myk;
    }
    int rank = 0;
#pragma unroll
    for (int m = 0; m < 64; m += 4) {
      u64 k0 = wb[m], k1 = wb[m + 1], k2 = wb[m + 2], k3 = wb[m + 3];
      rank += (int)(k0 < myk) + (int)(k1 < myk) + (int)(k2 < myk) + (int)(k3 < myk);
    }
    if (rank < KNN) wb[rank] = myk;
    u64 s15 = wb[15];
    if (lane < KNN) slot[p] = wb[lane];
    tau[p] = unmapmono((u32)(s15 >> 32));
    cnt[p] = 0;
  };

  for (int tb = 0; tb < NPTS; tb += TS) {
    __syncthreads();  // prev tile readers done
    for (int t = threadIdx.x; t < TS; t += 512) {
      const float* fr = fb + (size_t)(tb + t) * 6;
      const float x = fr[0], y = fr[1], z = fr[2];
      // sq with the EXACT rn op sequence used for sqi (d2 bit-compat)
      const float sq = __fadd_rn(__fadd_rn(__fmul_rn(x, x), __fmul_rn(y, y)),
                                 __fmul_rn(z, z));
      float4 c; c.x = x; c.y = y; c.z = z; c.w = sq;
      sc[t] = c;
    }
    __syncthreads();

    for (int jb0 = 0; jb0 < TS; jb0 += 64) {
      const int tl = jb0 + lane;
      const int j = tb + tl;
      const float4 c = sc[tl];
      const v2f cx2 = {c.x, c.x}, cy2 = {c.y, c.y}, cz2 = {c.z, c.z},
                sq2 = {c.w, c.w};
      v2f X = {xi[0], xi[1]};
      v2f Y = {yi[0], yi[1]};
      v2f Z = {zi[0], zi[1]};
      v2f SQ = {sqi[0], sqi[1]};
      v2f dot = X * cx2;
      dot = __builtin_elementwise_fma(Y, cy2, dot);
      dot = __builtin_elementwise_fma(Z, cz2, dot);
      v2f two = {2.0f, 2.0f};
      v2f d2v = (SQ + sq2) - two * dot;  // contract(off): rn each op
      float d2s[2] = {d2v.x, d2v.y};
#pragma unroll
      for (int p = 0; p < 2; ++p) {
        const bool pred = d2s[p] <= tau[p];
        const u64 bal = __ballot(pred);
        if (bal) {
          const int npass = __popcll(bal);
          if (cnt[p] + npass > CAP) flush(p);
          const int pos = cnt[p] + (int)__builtin_amdgcn_mbcnt_hi(
                                        (u32)(bal >> 32),
                                        __builtin_amdgcn_mbcnt_lo((u32)bal, 0));
          const u64 key = ((u64)__float_as_uint(d2s[p]) << 32) | (u32)j;  // RAW
          if (npass <= CAP) {
            if (pred) sbuf[wave][p][pos] = key;
            cnt[p] += npass;
          } else {  // npass in (48,64]: batch-0 bootstrap + pathological ties
            if (pred && pos < CAP) sbuf[wave][p][pos] = key;
            cnt[p] = CAP;
            flush(p);
            if (pred && pos >= CAP) sbuf[wave][p][pos - CAP] = key;
            cnt[p] = npass - CAP;
          }
        }
      }
    }
  }
#pragma unroll
  for (int p = 0; p < 2; ++p) flush(p);  // final merge -> slots hold winners

  // ---- fused enc1: x1[n] = relu(((Σ_{nbr ∪ self} feats) @ W1)*inv_deg + b1)
  float* fsc = (float*)&sbuf[wave][0][0];  // wave-private scratch
  float w1r[6];
#pragma unroll
  for (int k = 0; k < 6; ++k) w1r[k] = W1[k * 64 + lane];
  const float b1r = b1[lane];

#pragma unroll
  for (int p = 0; p < 2; ++p) {
    const int n = b * NPTS + ip[p];
    const int row = (lane < KNN) ? (int)(u32)slot[p] : ip[p];
    if (lane < KNN)
      nbr[(size_t)n * KNN + lane] = row;  // for enc23's gather
    if (lane < 17) {
      const float* fr = fb + (size_t)row * 6;
      float2 r0 = *(const float2*)(fr);
      float2 r1 = *(const float2*)(fr + 2);
      float2 r2 = *(const float2*)(fr + 4);
      fsc[lane * 6 + 0] = r0.x; fsc[lane * 6 + 1] = r0.y;
      fsc[lane * 6 + 2] = r1.x; fsc[lane * 6 + 3] = r1.y;
      fsc[lane * 6 + 4] = r2.x; fsc[lane * 6 + 5] = r2.y;
    }
    __syncthreads();  // all waves execute both iterations: barriers match
    if (lane < 6) {
      float s = 0.f;
#pragma unroll
      for (int t = 0; t < 17; ++t) s += fsc[t * 6 + lane];
      fsc[102 + lane] = s;
    }
    __syncthreads();
    float s = 0.f;
#pragma unroll
    for (int k = 0; k < 6; ++k) s = fmaf(fsc[102 + k], w1r[k], s);
    x1[(size_t)n * 64 + lane] = fmaxf(fmaf(s, INV_DEG, b1r), 0.f);
    __syncthreads();  // protect fsc reuse for p=1
  }
}

// ---------------------------------------------------------------------------
// T2: FUSED enc2+enc3. 16 pts/block, grid 2048 (coverage: 32768 ✓).
//   a1 = x1 + Σ_nbr x1  (gather, 16 thr/pt float4)
//   x2 = relu((a1@W2)*inv_deg + b2)  -> LDS tile (never hits global)
//   out = x2@Wf + bf
// Weights streamed through ONE 8KB LDS tile (4 tiles W2, 8 tiles Wf) so the
// block stays at 20KB (3 blocks/CU). Each wave owns 4 points end-to-end; xs
// rows are wave-private (no barrier needed between the two GEMMs beyond the
// tile-restage barriers). d_out written only at the end (in-place safe).
// ---------------------------------------------------------------------------
__global__ __launch_bounds__(256) void enc23_kernel(const float* __restrict__ x1,
                                                    const int* __restrict__ nbr,
                                                    const float* __restrict__ W2,
                                                    const float* __restrict__ b2,
                                                    const float* __restrict__ Wf,
                                                    const float* __restrict__ bf,
                                                    float* __restrict__ out) {
  __shared__ float a1s[16][64];  // 4 KB
  __shared__ v2f wt[16][64];     // 8 KB streaming weight tile
  __shared__ float xs[16][128];  // 8 KB x2 tile
  const int tid = threadIdx.x;
  const int n0 = blockIdx.x * 16;
  const int gb = n0 & ~(NPTS - 1);
  const int wave = tid >> 6, lane = tid & 63;

  // gather + aggregate x1 for 16 points (16 threads/point, float4 channels)
  {
    const int p = tid >> 4, c4 = tid & 15;
    const int n = n0 + p;
    const int* nb = nbr + (size_t)n * KNN;
    float4 s = ((const float4*)(x1 + (size_t)n * 64))[c4];
#pragma unroll
    for (int t = 0; t < KNN; ++t) {
      float4 v = ((const float4*)(x1 + (size_t)(gb + nb[t]) * 64))[c4];
      s.x += v.x; s.y += v.y; s.z += v.z; s.w += v.w;
    }
    *((float4*)&a1s[p][c4 * 4]) = s;
  }

  const int p0 = wave * 4;
  const float bx = b2[lane], by = b2[lane + 64];

  // ---- GEMM1: x2 = relu((a1@W2)*inv_deg + b2), W2 streamed in 4 tiles ----
  v2f acc[4];
#pragma unroll
  for (int i = 0; i < 4; ++i) acc[i] = (v2f){0, 0};
  for (int kt = 0; kt < 64; kt += 16) {
    __syncthreads();  // prev tile readers done (also covers initial gather)
#pragma unroll
    for (int i = 0; i < 4; ++i) {
      const int e = tid + 256 * i;  // 1024 v2f
      const int k = e >> 6, l = e & 63;
      v2f w;
      w.x = W2[(kt + k) * 128 + l];
      w.y = W2[(kt + k) * 128 + 64 + l];
      wt[k][l] = w;
    }
    __syncthreads();
    for (int kk = 0; kk < 16; kk += 4) {
      float4 a[4];
#pragma unroll
      for (int i = 0; i < 4; ++i) a[i] = *(const float4*)&a1s[p0 + i][kt + kk];
#pragma unroll
      for (int j = 0; j < 4; ++j) {
        const v2f w = wt[kk + j][lane];
#pragma unroll
        for (int i = 0; i < 4; ++i) {
          const float e = j == 0 ? a[i].x : j == 1 ? a[i].y : j == 2 ? a[i].z
                                                                     : a[i].w;
          v2f v = {e, e};
          acc[i] = __builtin_elementwise_fma(v, w, acc[i]);
        }
      }
    }
  }
#pragma unroll
  for (int pi = 0; pi < 4; ++pi) {  // wave-private xs rows: no barrier needed
    xs[p0 + pi][lane] = fmaxf(fmaf(acc[pi].x, INV_DEG, bx), 0.f);
    xs[p0 + pi][lane + 64] = fmaxf(fmaf(acc[pi].y, INV_DEG, by), 0.f);
  }

  // ---- GEMM2: out = x2@Wf + bf, Wf streamed in 8 tiles ----
  v2f facc[4];
#pragma unroll
  for (int i = 0; i < 4; ++i) facc[i] = (v2f){0, 0};
  for (int jt = 0; jt < 128; jt += 16) {
    __syncthreads();  // prev tile readers done
#pragma unroll
    for (int i = 0; i < 4; ++i) {
      const int e = tid + 256 * i;
      const int j = e >> 6, l = e & 63;
      v2f w;
      w.x = Wf[(jt + j) * 128 + l];
      w.y = Wf[(jt + j) * 128 + 64 + l];
      wt[j][l] = w;
    }
    __syncthreads();
    for (int jj = 0; jj < 16; jj += 4) {
      float4 a[4];
#pragma unroll
      for (int i = 0; i < 4; ++i) a[i] = *(const float4*)&xs[p0 + i][jt + jj];
#pragma unroll
      for (int j2 = 0; j2 < 4; ++j2) {
        const v2f w = wt[jj + j2][lane];
#pragma unroll
        for (int i = 0; i < 4; ++i) {
          const float e = j2 == 0 ? a[i].x : j2 == 1 ? a[i].y : j2 == 2 ? a[i].z
                                                                        : a[i].w;
          v2f v = {e, e};
          facc[i] = __builtin_elementwise_fma(v, w, facc[i]);
        }
      }
    }
  }
  const float fx = bf[lane], fy = bf[lane + 64];
#pragma unroll
  for (int pi = 0; pi < 4; ++pi) {
    float* row = out + (size_t)(n0 + p0 + pi) * 128;
    row[lane] = facc[pi].x + fx;
    row[lane + 64] = facc[pi].y + fy;
  }
}

// ---------------------------------------------------------------------------
// Workspace: nbr@0 (2MB), x1@2MB (8MB). x2 never materialized in global.
// ---------------------------------------------------------------------------
extern "C" void kernel_launch(void* const* d_in, const int* in_sizes, int n_in,
                              void* d_out, int out_size, void* d_ws, size_t ws_size,
                              hipStream_t stream) {
  const float* feats = (const float*)d_in[0];
  const float* W1 = (const float*)d_in[1];
  const float* b1 = (const float*)d_in[2];
  const float* W2 = (const float*)d_in[3];
  const float* b2 = (const float*)d_in[4];
  const float* Wf = (const float*)d_in[5];
  const float* bf = (const float*)d_in[6];
  float* out = (float*)d_out;

  char* ws = (char*)d_ws;
  int* nbr = (int*)ws;
  float* x1 = (float*)(ws + (size_t)(2 << 20));

  knn_kernel<<<2048, 512, 0, stream>>>(feats, W1, b1, nbr, x1);
  enc23_kernel<<<2048, 256, 0, stream>>>(x1, nbr, W2, b2, Wf, bf, out);
}

// Round 11
// 229.149 us; speedup vs baseline: 1.0468x; 1.0468x over previous
//
#include <hip/hip_runtime.h>
#include <cstdint>
#include <cstddef>

#define NPTS 4096
#define KNN  16
#define INV_DEG (1.0f / 17.0f)
#define CAP  48   // knn per-point candidate buffer (entries [48..64) = slot staging)
#define TS   512  // candidate tile (float4 x/y/z/sq = 8 KB). R10: TS=256 regressed.

typedef unsigned long long u64;
typedef unsigned int u32;
typedef float v2f __attribute__((ext_vector_type(2)));

// Raw keys: (f32bits(d2) << 32) | j. Interpreted as f64 this is
// order-isomorphic to (d2 asc, idx asc) for all finite d2 (see R11 notes):
// positive d2 -> positive f64 (idx in low mantissa bits ascends); negative d2
// -> negative f64 with magnitude ascending = d2 descending = correct.
// Sentinels below have exponent 0x7F8 (not 0x7FF) -> finite huge, sort last.
#define UNUSED_K 0x7F800000FFFFFFFFull
#define SELF_K   0x7F800000FFFFFFFEull

__device__ __forceinline__ double as_f64(u64 k) { return __longlong_as_double((long long)k); }

// ---------------------------------------------------------------------------
// K1: exact KNN (top-16 smallest d2, tie -> lower index) + fused enc1.
// Ledger: (R3) no min-waves hint -> 45MB scratch spill; (R4) flush = LDS
// rank-select, NOT shfl bitonic; (R5/R6) 16KB/block -> ~3 blocks/CU, 72% occ;
// (R7/R8 FAIL) grid must cover all 32768 pts; (R10) TS=256 bought no 4th
// block, cost 10us of barriers. R11: flush compares via v_cmp_lt_f64 (1 inst
// vs u64 3-op chain); mono map/unmap deleted.
// ---------------------------------------------------------------------------
__global__ __launch_bounds__(512) void knn_kernel(const float* __restrict__ feats,
                                                  const float* __restrict__ W1,
                                                  const float* __restrict__ b1,
                                                  int* __restrict__ nbr,
                                                  float* __restrict__ x1) {
#pragma clang fp contract(off)
  __shared__ float4 sc[TS];       // 8 KB: {x, y, z, sq}
  __shared__ u64 sbuf[8][2][64];  // 8 KB

  const int b = blockIdx.x >> 8;
  const int pbase = (blockIdx.x & 255) * 16;
  const float* fb = feats + (size_t)b * NPTS * 6;
  const int wave = threadIdx.x >> 6;
  const int lane = threadIdx.x & 63;

  int ip[2];
  float xi[2], yi[2], zi[2], sqi[2], tau[2];
  u64 slot[2];
  int cnt[2];
#pragma unroll
  for (int p = 0; p < 2; ++p) {
    ip[p] = pbase + wave * 2 + p;
    const float* fr = fb + (size_t)ip[p] * 6;
    xi[p] = fr[0]; yi[p] = fr[1]; zi[p] = fr[2];
    sqi[p] = __fadd_rn(__fadd_rn(__fmul_rn(xi[p], xi[p]), __fmul_rn(yi[p], yi[p])),
                       __fmul_rn(zi[p], zi[p]));
    tau[p] = __uint_as_float(0x7f800000u);  // +inf: batch 0 all-pass bootstraps
    slot[p] = UNUSED_K;
    cnt[p] = 0;
  }

  // LDS rank-select merge of {<=48 buffered} U {16 slots}, all raw keys.
  // Rank via f64 compares. Identical-key groups (sentinels) share a rank but
  // that rank is always >= #real >= 16, so wb[0..15] writers are unique.
  auto flush = [&](int p) {
    u64* wb = &sbuf[wave][p][0];
    if (lane >= cnt[p] && lane < CAP) wb[lane] = UNUSED_K;  // clear unused
    if (lane < KNN) wb[CAP + lane] = slot[p];               // stage slots
    u64 myk = wb[lane];
    if ((u32)myk == (u32)ip[p]) {  // neutralize self (sentinel lows != ip)
      myk = SELF_K;
      wb[lane] = SELF_K;
    }
    const double dm = as_f64(myk);
    int rank = 0;
#pragma unroll
    for (int m = 0; m < 64; m += 4) {
      const double k0 = as_f64(wb[m]), k1 = as_f64(wb[m + 1]);
      const double k2 = as_f64(wb[m + 2]), k3 = as_f64(wb[m + 3]);
      rank += (int)(k0 < dm) + (int)(k1 < dm) + (int)(k2 < dm) + (int)(k3 < dm);
    }
    if (rank < KNN) wb[rank] = myk;
    u64 s15 = wb[15];
    if (lane < KNN) slot[p] = wb[lane];
    tau[p] = __uint_as_float((u32)(s15 >> 32));  // raw hi bits ARE d2 bits
    cnt[p] = 0;
  };

  for (int tb = 0; tb < NPTS; tb += TS) {
    __syncthreads();  // prev tile readers done
    for (int t = threadIdx.x; t < TS; t += 512) {
      const float* fr = fb + (size_t)(tb + t) * 6;
      const float x = fr[0], y = fr[1], z = fr[2];
      // sq with the EXACT rn op sequence used for sqi (d2 bit-compat)
      const float sq = __fadd_rn(__fadd_rn(__fmul_rn(x, x), __fmul_rn(y, y)),
                                 __fmul_rn(z, z));
      float4 c; c.x = x; c.y = y; c.z = z; c.w = sq;
      sc[t] = c;
    }
    __syncthreads();

    for (int jb0 = 0; jb0 < TS; jb0 += 64) {
      const int tl = jb0 + lane;
      const int j = tb + tl;
      const float4 c = sc[tl];
      const v2f cx2 = {c.x, c.x}, cy2 = {c.y, c.y}, cz2 = {c.z, c.z},
                sq2 = {c.w, c.w};
      v2f X = {xi[0], xi[1]};
      v2f Y = {yi[0], yi[1]};
      v2f Z = {zi[0], zi[1]};
      v2f SQ = {sqi[0], sqi[1]};
      v2f dot = X * cx2;
      dot = __builtin_elementwise_fma(Y, cy2, dot);
      dot = __builtin_elementwise_fma(Z, cz2, dot);
      v2f two = {2.0f, 2.0f};
      v2f d2v = (SQ + sq2) - two * dot;  // contract(off): rn each op
      float d2s[2] = {d2v.x, d2v.y};
#pragma unroll
      for (int p = 0; p < 2; ++p) {
        const bool pred = d2s[p] <= tau[p];
        const u64 bal = __ballot(pred);
        if (bal) {
          const int npass = __popcll(bal);
          if (cnt[p] + npass > CAP) flush(p);
          const int pos = cnt[p] + (int)__builtin_amdgcn_mbcnt_hi(
                                        (u32)(bal >> 32),
                                        __builtin_amdgcn_mbcnt_lo((u32)bal, 0));
          const u64 key = ((u64)__float_as_uint(d2s[p]) << 32) | (u32)j;  // RAW
          if (npass <= CAP) {
            if (pred) sbuf[wave][p][pos] = key;
            cnt[p] += npass;
          } else {  // npass in (48,64]: batch-0 bootstrap + pathological ties
            if (pred && pos < CAP) sbuf[wave][p][pos] = key;
            cnt[p] = CAP;
            flush(p);
            if (pred && pos >= CAP) sbuf[wave][p][pos - CAP] = key;
            cnt[p] = npass - CAP;
          }
        }
      }
    }
  }
#pragma unroll
  for (int p = 0; p < 2; ++p) flush(p);  // final merge -> slots hold winners

  // ---- fused enc1: x1[n] = relu(((Σ_{nbr ∪ self} feats) @ W1)*inv_deg + b1)
  float* fsc = (float*)&sbuf[wave][0][0];  // wave-private scratch
  float w1r[6];
#pragma unroll
  for (int k = 0; k < 6; ++k) w1r[k] = W1[k * 64 + lane];
  const float b1r = b1[lane];

#pragma unroll
  for (int p = 0; p < 2; ++p) {
    const int n = b * NPTS + ip[p];
    const int row = (lane < KNN) ? (int)(u32)slot[p] : ip[p];
    if (lane < KNN)
      nbr[(size_t)n * KNN + lane] = row;  // for enc23's gather
    if (lane < 17) {
      const float* fr = fb + (size_t)row * 6;
      float2 r0 = *(const float2*)(fr);
      float2 r1 = *(const float2*)(fr + 2);
      float2 r2 = *(const float2*)(fr + 4);
      fsc[lane * 6 + 0] = r0.x; fsc[lane * 6 + 1] = r0.y;
      fsc[lane * 6 + 2] = r1.x; fsc[lane * 6 + 3] = r1.y;
      fsc[lane * 6 + 4] = r2.x; fsc[lane * 6 + 5] = r2.y;
    }
    __syncthreads();  // all waves execute both iterations: barriers match
    if (lane < 6) {
      float s = 0.f;
#pragma unroll
      for (int t = 0; t < 17; ++t) s += fsc[t * 6 + lane];
      fsc[102 + lane] = s;
    }
    __syncthreads();
    float s = 0.f;
#pragma unroll
    for (int k = 0; k < 6; ++k) s = fmaf(fsc[102 + k], w1r[k], s);
    x1[(size_t)n * 64 + lane] = fmaxf(fmaf(s, INV_DEG, b1r), 0.f);
    __syncthreads();  // protect fsc reuse for p=1
  }
}

// ---------------------------------------------------------------------------
// T2: FUSED enc2+enc3 (R10 verbatim — best measured tail). 16 pts/block,
// grid 2048. x2 never leaves LDS; weights streamed through one 8KB tile.
// ---------------------------------------------------------------------------
__global__ __launch_bounds__(256) void enc23_kernel(const float* __restrict__ x1,
                                                    const int* __restrict__ nbr,
                                                    const float* __restrict__ W2,
                                                    const float* __restrict__ b2,
                                                    const float* __restrict__ Wf,
                                                    const float* __restrict__ bf,
                                                    float* __restrict__ out) {
  __shared__ float a1s[16][64];  // 4 KB
  __shared__ v2f wt[16][64];     // 8 KB streaming weight tile
  __shared__ float xs[16][128];  // 8 KB x2 tile
  const int tid = threadIdx.x;
  const int n0 = blockIdx.x * 16;
  const int gb = n0 & ~(NPTS - 1);
  const int wave = tid >> 6, lane = tid & 63;

  // gather + aggregate x1 for 16 points (16 threads/point, float4 channels)
  {
    const int p = tid >> 4, c4 = tid & 15;
    const int n = n0 + p;
    const int* nb = nbr + (size_t)n * KNN;
    float4 s = ((const float4*)(x1 + (size_t)n * 64))[c4];
#pragma unroll
    for (int t = 0; t < KNN; ++t) {
      float4 v = ((const float4*)(x1 + (size_t)(gb + nb[t]) * 64))[c4];
      s.x += v.x; s.y += v.y; s.z += v.z; s.w += v.w;
    }
    *((float4*)&a1s[p][c4 * 4]) = s;
  }

  const int p0 = wave * 4;
  const float bx = b2[lane], by = b2[lane + 64];

  // ---- GEMM1: x2 = relu((a1@W2)*inv_deg + b2), W2 streamed in 4 tiles ----
  v2f acc[4];
#pragma unroll
  for (int i = 0; i < 4; ++i) acc[i] = (v2f){0, 0};
  for (int kt = 0; kt < 64; kt += 16) {
    __syncthreads();  // prev tile readers done (also covers initial gather)
#pragma unroll
    for (int i = 0; i < 4; ++i) {
      const int e = tid + 256 * i;  // 1024 v2f
      const int k = e >> 6, l = e & 63;
      v2f w;
      w.x = W2[(kt + k) * 128 + l];
      w.y = W2[(kt + k) * 128 + 64 + l];
      wt[k][l] = w;
    }
    __syncthreads();
    for (int kk = 0; kk < 16; kk += 4) {
      float4 a[4];
#pragma unroll
      for (int i = 0; i < 4; ++i) a[i] = *(const float4*)&a1s[p0 + i][kt + kk];
#pragma unroll
      for (int j = 0; j < 4; ++j) {
        const v2f w = wt[kk + j][lane];
#pragma unroll
        for (int i = 0; i < 4; ++i) {
          const float e = j == 0 ? a[i].x : j == 1 ? a[i].y : j == 2 ? a[i].z
                                                                     : a[i].w;
          v2f v = {e, e};
          acc[i] = __builtin_elementwise_fma(v, w, acc[i]);
        }
      }
    }
  }
#pragma unroll
  for (int pi = 0; pi < 4; ++pi) {  // wave-private xs rows: no barrier needed
    xs[p0 + pi][lane] = fmaxf(fmaf(acc[pi].x, INV_DEG, bx), 0.f);
    xs[p0 + pi][lane + 64] = fmaxf(fmaf(acc[pi].y, INV_DEG, by), 0.f);
  }

  // ---- GEMM2: out = x2@Wf + bf, Wf streamed in 8 tiles ----
  v2f facc[4];
#pragma unroll
  for (int i = 0; i < 4; ++i) facc[i] = (v2f){0, 0};
  for (int jt = 0; jt < 128; jt += 16) {
    __syncthreads();  // prev tile readers done
#pragma unroll
    for (int i = 0; i < 4; ++i) {
      const int e = tid + 256 * i;
      const int j = e >> 6, l = e & 63;
      v2f w;
      w.x = Wf[(jt + j) * 128 + l];
      w.y = Wf[(jt + j) * 128 + 64 + l];
      wt[j][l] = w;
    }
    __syncthreads();
    for (int jj = 0; jj < 16; jj += 4) {
      float4 a[4];
#pragma unroll
      for (int i = 0; i < 4; ++i) a[i] = *(const float4*)&xs[p0 + i][jt + jj];
#pragma unroll
      for (int j2 = 0; j2 < 4; ++j2) {
        const v2f w = wt[jj + j2][lane];
#pragma unroll
        for (int i = 0; i < 4; ++i) {
          const float e = j2 == 0 ? a[i].x : j2 == 1 ? a[i].y : j2 == 2 ? a[i].z
                                                                        : a[i].w;
          v2f v = {e, e};
          facc[i] = __builtin_elementwise_fma(v, w, facc[i]);
        }
      }
    }
  }
  const float fx = bf[lane], fy = bf[lane + 64];
#pragma unroll
  for (int pi = 0; pi < 4; ++pi) {
    float* row = out + (size_t)(n0 + p0 + pi) * 128;
    row[lane] = facc[pi].x + fx;
    row[lane + 64] = facc[pi].y + fy;
  }
}

// ---------------------------------------------------------------------------
// Workspace: nbr@0 (2MB), x1@2MB (8MB). x2 never materialized in global.
// ---------------------------------------------------------------------------
extern "C" void kernel_launch(void* const* d_in, const int* in_sizes, int n_in,
                              void* d_out, int out_size, void* d_ws, size_t ws_size,
                              hipStream_t stream) {
  const float* feats = (const float*)d_in[0];
  const float* W1 = (const float*)d_in[1];
  const float* b1 = (const float*)d_in[2];
  const float* W2 = (const float*)d_in[3];
  const float* b2 = (const float*)d_in[4];
  const float* Wf = (const float*)d_in[5];
  const float* bf = (const float*)d_in[6];
  float* out = (float*)d_out;

  char* ws = (char*)d_ws;
  int* nbr = (int*)ws;
  float* x1 = (float*)(ws + (size_t)(2 << 20));

  knn_kernel<<<2048, 512, 0, stream>>>(feats, W1, b1, nbr, x1);
  enc23_kernel<<<2048, 256, 0, stream>>>(x1, nbr, W2, b2, Wf, bf, out);
}